// Round 5
// baseline (178.194 us; speedup 1.0000x reference)
//
#include <hip/hip_runtime.h>
#include <hip/hip_bf16.h>

// B=64, S=2048, D=256, VOCAB=288. M=131072, T=288 (derived host-side).
// Key insight: only 7*T = 2016 distinct h rows exist.
//   prep:  Htab[day*T+tod] = relu(W1[day]+W1[7+tod]+b1)  bf16 [2016][256] (1 MB)
//          W2S = W2 in MFMA-fragment-linear bf16 (1KB-burst B loads)
//   main:  gather Htab rows -> wave-private LDS -> A-frags; GEMM 16x16x32 bf16.
// No __syncthreads anywhere in the main kernel; 33 KB LDS/block -> 4 blocks/CU.

typedef __bf16 bf16x4 __attribute__((ext_vector_type(4)));
typedef __bf16 bf16x8 __attribute__((ext_vector_type(8)));
typedef float  f32x4  __attribute__((ext_vector_type(4)));

#define M_TOTAL   131072
#define BM        128            // rows per block (4 waves x 32 rows)
#define HPAD      258            // 256 + 2-element pad (bank decorrelation)

// ws: [0,131072) W2S ; [131072, 131072+1032192) Htab (7*288*256*2 B) ; then flag

// ---- prep: Htab + W2S + TE dtype probe ------------------------------------
__global__ __launch_bounds__(64) void prep_all(const float* __restrict__ W1,
                                               const float* __restrict__ b1,
                                               const float* __restrict__ W2,
                                               __bf16* __restrict__ W2S,
                                               __bf16* __restrict__ Htab,
                                               const int* __restrict__ TE32,
                                               int* __restrict__ flag, int T) {
    const int b = blockIdx.x, lane = threadIdx.x;
    const int nTab = 7 * T;                    // 2016
    if (b < nTab) {
        // one h-table row per block: coalesced 1KB reads, 512B bf16 write
        const float* __restrict__ wa = W1 + (b / T) * 256;
        const float* __restrict__ wb = W1 + (7 + b % T) * 256;
        f32x4 a = *(const f32x4*)(wa + lane * 4);
        f32x4 c = *(const f32x4*)(wb + lane * 4);
        f32x4 d = *(const f32x4*)(b1 + lane * 4);
        bf16x4 h;
#pragma unroll
        for (int j = 0; j < 4; ++j) h[j] = (__bf16)fmaxf(a[j] + c[j] + d[j], 0.0f);
        *(bf16x4*)(Htab + b * 256 + lane * 4) = h;
    } else {
        const int wb = b - nTab;               // 0..63
        // W2S chunk c = (nt*8+ks)*64+l ; element j -> W2[ks*32+(l>>4)*8+j][nt*16+(l&15)]
#pragma unroll
        for (int q = 0; q < 2; ++q) {
            int c = (wb * 64 + lane) * 2 + q;  // 0..8191
            int l = c & 63, ksnt = c >> 6;
            int ks = ksnt & 7, nt = ksnt >> 3;
            int n  = nt * 16 + (l & 15);
            int k0 = ks * 32 + (l >> 4) * 8;
            bf16x8 w;
#pragma unroll
            for (int j = 0; j < 8; ++j) w[j] = (__bf16)W2[(k0 + j) * 256 + n];
            *(bf16x8*)(W2S + c * 8) = w;
        }
        // TE dtype probe (block nTab only): int64 => odd words all zero
        if (wb == 0) {
            int v = 0;
            for (int i = lane; i < 2048; i += 64) v |= TE32[2 * i + 1];
            unsigned long long nz = __ballot(v != 0);
            if (lane == 0) *flag = (nz == 0ull) ? 1 : 0;
        }
    }
}

// ---- main ------------------------------------------------------------------
__global__ __launch_bounds__(256, 4) void temb_gemm(
        const int*   __restrict__ TE32,  // [M,2] int32 or int64 word view
        const __bf16* __restrict__ Htab, // [7*T][256] bf16
        const __bf16* __restrict__ W2S,  // fragment-linear bf16
        const float* __restrict__ b2,    // [256]
        const int*   __restrict__ flag,  // 1 if TE is int64
        float* __restrict__ out, int T)  // [M,256] fp32
{
    __shared__ __bf16 hbuf[4][16 * HPAD];   // 8.25 KB per wave, wave-private
    const int is64 = *flag;                 // wave-uniform
    const int wave = threadIdx.x >> 6;
    const int lane = threadIdx.x & 63;
    const int m    = lane & 15;             // A row in tile / C col in tile
    const int quad = lane >> 4;             // k-chunk / C row-group
    const int half = lane >> 5;             // row selector in paired loads
    const int c32  = lane & 31;             // 16B chunk within a row
    const int rowBase = blockIdx.x * BM + wave * 32;
    __bf16* __restrict__ myH = &hbuf[wave][0];

    // ---- phase 0: table row index for this wave's 32 rows (lanes 0..31) ----
    int code = 0;
    if (lane < 32) {
        int day, tod;
        if (is64) { int4 te = *(const int4*)(TE32 + 4 * (rowBase + lane)); day = te.x; tod = te.z; }
        else      { int2 te = *(const int2*)(TE32 + 2 * (rowBase + lane)); day = te.x; tod = te.y; }
        code = (day % 7) * T + tod % T;
    }

    // ---- phase 1+2: per m-tile, stage 16 Htab rows -> LDS -> A-frags -------
    // A layout: A[m = lane&15][k = quad*8 + j]; no barriers (wave-local LDS)
    bf16x8 afrag[2][8];
#pragma unroll
    for (int t = 0; t < 2; ++t) {
#pragma unroll
        for (int g = 0; g < 8; ++g) {       // 2 rows per wave-instruction
            const int ridx = __shfl(code, t * 16 + 2 * g + half);
            bf16x8 hv = *(const bf16x8*)(Htab + ridx * 256 + c32 * 8);
            *(bf16x8*)(myH + (2 * g + half) * HPAD + c32 * 8) = hv;
        }
#pragma unroll
        for (int ks = 0; ks < 8; ++ks)
            afrag[t][ks] = *(const bf16x8*)(myH + m * HPAD + ks * 32 + quad * 8);
    }

    // per-lane bias: b2[nt*16 + m]
    float b2r[16];
#pragma unroll
    for (int nt = 0; nt < 16; ++nt) b2r[nt] = b2[nt * 16 + m];

    // ---- phase 3: N loop; B-frag loads are contiguous 1KB bursts -----------
    const __bf16* __restrict__ wp = W2S + lane * 8;
#pragma unroll 4
    for (int nt = 0; nt < 16; ++nt) {
        f32x4 acc0 = {0.f, 0.f, 0.f, 0.f};
        f32x4 acc1 = {0.f, 0.f, 0.f, 0.f};
#pragma unroll
        for (int ks = 0; ks < 8; ++ks) {
            bf16x8 bfrag = *(const bf16x8*)(wp + (nt * 8 + ks) * 512);
            acc0 = __builtin_amdgcn_mfma_f32_16x16x32_bf16(afrag[0][ks], bfrag, acc0, 0, 0, 0);
            acc1 = __builtin_amdgcn_mfma_f32_16x16x32_bf16(afrag[1][ks], bfrag, acc1, 0, 0, 0);
        }
        // C/D layout: col = lane&15, row = quad*4 + reg
        const int ncol = nt * 16 + m;
        const float bias = b2r[nt];
#pragma unroll
        for (int r = 0; r < 4; ++r) {
            const int row0 = rowBase + quad * 4 + r;
            out[row0 * 256 + ncol]        = acc0[r] + bias;
            out[(row0 + 16) * 256 + ncol] = acc1[r] + bias;
        }
    }
}

extern "C" void kernel_launch(void* const* d_in, const int* in_sizes, int n_in,
                              void* d_out, int out_size, void* d_ws, size_t ws_size,
                              hipStream_t stream) {
    const int*   TE = (const int*)  d_in[0];   // [B,S,2] integer words
    const float* W1 = (const float*)d_in[2];   // [7+T,256]
    const float* b1 = (const float*)d_in[3];   // [256]
    const float* W2 = (const float*)d_in[4];   // [256,256]
    const float* b2 = (const float*)d_in[5];   // [256]
    const int T = in_sizes[2] / 256 - 7;       // 288 (W1 has 7+T rows)

    __bf16* W2S  = (__bf16*)d_ws;                         // 128 KB
    __bf16* Htab = (__bf16*)((char*)d_ws + 131072);       // 7*T*256*2 = 1032192 B
    int*    flag = (int*)((char*)d_ws + 131072 + (size_t)7 * T * 256 * 2);
    float*  out  = (float*)d_out;

    prep_all<<<7 * T + 64, 64, 0, stream>>>(W1, b1, W2, W2S, Htab, TE, flag, T);
    temb_gemm<<<M_TOTAL / BM, 256, 0, stream>>>(TE, Htab, W2S, b2, flag, out, T);
}

// Round 6
// 165.230 us; speedup vs baseline: 1.0785x; 1.0785x over previous
//
#include <hip/hip_runtime.h>
#include <hip/hip_bf16.h>

// B=64, S=2048, D=256, VOCAB=288. M=131072, T derived host-side.
// Htab[day*T+tod] = relu(W1[day]+W1[7+tod]+b1) bf16 [7T][256]  (only 2016 rows!)
// W2S = W2 swizzled to MFMA fragment-linear bf16.
// Main: OPERAND-SWAPPED mfma: A-op = W2 frag (from LDS, block-shared),
//       B-op = h frag (direct from Htab). D gives each lane 4 consecutive
//       output COLS of one row -> contiguous dwordx4 stores.

typedef __bf16 bf16x4 __attribute__((ext_vector_type(4)));
typedef __bf16 bf16x8 __attribute__((ext_vector_type(8)));
typedef float  f32x4  __attribute__((ext_vector_type(4)));

#define M_TOTAL   131072
#define BM        128            // rows per block (4 waves x 32 rows)

// ws: [0,131072) W2S ; [131072, +7T*512) Htab ; then flag

// ---- prep: Htab + W2S + TE dtype probe (unchanged from R5, verified) -------
__global__ __launch_bounds__(64) void prep_all(const float* __restrict__ W1,
                                               const float* __restrict__ b1,
                                               const float* __restrict__ W2,
                                               __bf16* __restrict__ W2S,
                                               __bf16* __restrict__ Htab,
                                               const int* __restrict__ TE32,
                                               int* __restrict__ flag, int T) {
    const int b = blockIdx.x, lane = threadIdx.x;
    const int nTab = 7 * T;
    if (b < nTab) {
        const float* __restrict__ wa = W1 + (b / T) * 256;
        const float* __restrict__ wb = W1 + (7 + b % T) * 256;
        f32x4 a = *(const f32x4*)(wa + lane * 4);
        f32x4 c = *(const f32x4*)(wb + lane * 4);
        f32x4 d = *(const f32x4*)(b1 + lane * 4);
        bf16x4 h;
#pragma unroll
        for (int j = 0; j < 4; ++j) h[j] = (__bf16)fmaxf(a[j] + c[j] + d[j], 0.0f);
        *(bf16x4*)(Htab + b * 256 + lane * 4) = h;
    } else {
        const int wb = b - nTab;               // 0..63
        // W2S chunk c = (nt*8+ks)*64+l ; elem j -> W2[ks*32+(l>>4)*8+j][nt*16+(l&15)]
#pragma unroll
        for (int q = 0; q < 2; ++q) {
            int c = (wb * 64 + lane) * 2 + q;  // 0..8191
            int l = c & 63, ksnt = c >> 6;
            int ks = ksnt & 7, nt = ksnt >> 3;
            int n  = nt * 16 + (l & 15);
            int k0 = ks * 32 + (l >> 4) * 8;
            bf16x8 w;
#pragma unroll
            for (int j = 0; j < 8; ++j) w[j] = (__bf16)W2[(k0 + j) * 256 + n];
            *(bf16x8*)(W2S + c * 8) = w;
        }
        if (wb == 0) {  // TE dtype probe: int64 => odd int32 words all zero
            int v = 0;
            for (int i = lane; i < 2048; i += 64) v |= TE32[2 * i + 1];
            unsigned long long nz = __ballot(v != 0);
            if (lane == 0) *flag = (nz == 0ull) ? 1 : 0;
        }
    }
}

// ---- main ------------------------------------------------------------------
__global__ __launch_bounds__(256, 3) void temb_gemm(
        const int*   __restrict__ TE32,  // [M,2] int32 or int64 word view
        const __bf16* __restrict__ Htab, // [7T][256] bf16
        const __bf16* __restrict__ W2S,  // fragment-linear bf16 (128 KB)
        const float* __restrict__ b2,    // [256]
        const int*   __restrict__ flag,  // 1 if TE is int64
        float* __restrict__ out, int T)  // [M,256] fp32
{
    __shared__ __bf16 Bs[4 * 8 * 512];   // 32 KB: one group = 4 n-tiles of W2 frags

    const int is64 = *flag;              // wave-uniform
    const int tid  = threadIdx.x;
    const int wave = tid >> 6;
    const int lane = tid & 63;
    const int m    = lane & 15;
    const int quad = lane >> 4;
    const int rowBase = blockIdx.x * BM + wave * 32;

    // ---- h fragments as MFMA B-operand: lane holds h[row=rowBase+t*16+m][k=ks*32+quad*8+j]
    int code[2];
#pragma unroll
    for (int t = 0; t < 2; ++t) {
        const int row = rowBase + t * 16 + m;
        int day, tod;
        if (is64) { int4 te = *(const int4*)(TE32 + 4 * row); day = te.x; tod = te.z; }
        else      { int2 te = *(const int2*)(TE32 + 2 * row); day = te.x; tod = te.y; }
        code[t] = (day % 7) * T + (tod % T);
    }
    bf16x8 hfrag[2][8];
#pragma unroll
    for (int t = 0; t < 2; ++t)
#pragma unroll
        for (int ks = 0; ks < 8; ++ks)
            hfrag[t][ks] = *(const bf16x8*)(Htab + code[t] * 256 + ks * 32 + quad * 8);

    // ---- staging pipeline: group g = n-tiles 4g..4g+3 (32 KB of W2S) -------
    const bf16x8* __restrict__ gsrc = (const bf16x8*)W2S + tid;  // + q*256 + g*2048
    bf16x8* __restrict__ ldst = (bf16x8*)Bs + tid;               // + q*256
    const bf16x8* __restrict__ lsrc = (const bf16x8*)Bs;

    bf16x8 stage[8];
#pragma unroll
    for (int q = 0; q < 8; ++q) stage[q] = gsrc[q * 256];        // group 0

    for (int g = 0; g < 4; ++g) {
#pragma unroll
        for (int q = 0; q < 8; ++q) ldst[q * 256] = stage[q];
        __syncthreads();                       // Bs[g] visible to all waves
        if (g < 3) {                           // prefetch next group into regs
#pragma unroll
            for (int q = 0; q < 8; ++q) stage[q] = gsrc[(g + 1) * 2048 + q * 256];
        }
#pragma unroll
        for (int ntl = 0; ntl < 4; ++ntl) {
            const int nt = g * 4 + ntl;
            f32x4 acc0 = {0.f, 0.f, 0.f, 0.f};
            f32x4 acc1 = {0.f, 0.f, 0.f, 0.f};
#pragma unroll
            for (int ks = 0; ks < 8; ++ks) {
                bf16x8 wfrag = lsrc[(ntl * 8 + ks) * 64 + lane];   // A-operand (W2)
                acc0 = __builtin_amdgcn_mfma_f32_16x16x32_bf16(wfrag, hfrag[0][ks], acc0, 0, 0, 0);
                acc1 = __builtin_amdgcn_mfma_f32_16x16x32_bf16(wfrag, hfrag[1][ks], acc1, 0, 0, 0);
            }
            // D[m=quad*4+r][n=lane&15] = out[rowBase+t*16+(lane&15)][nt*16+quad*4+r]
            const f32x4 bias = *(const f32x4*)(b2 + nt * 16 + quad * 4);
            f32x4 v0, v1;
#pragma unroll
            for (int r = 0; r < 4; ++r) { v0[r] = acc0[r] + bias[r]; v1[r] = acc1[r] + bias[r]; }
            float* p0 = out + (rowBase + m) * 256 + nt * 16 + quad * 4;
            *(f32x4*)p0 = v0;
            *(f32x4*)(p0 + 16 * 256) = v1;
        }
        __syncthreads();                       // all waves done reading Bs[g]
    }
}

extern "C" void kernel_launch(void* const* d_in, const int* in_sizes, int n_in,
                              void* d_out, int out_size, void* d_ws, size_t ws_size,
                              hipStream_t stream) {
    const int*   TE = (const int*)  d_in[0];   // [B,S,2] integer words
    const float* W1 = (const float*)d_in[2];   // [7+T,256]
    const float* b1 = (const float*)d_in[3];   // [256]
    const float* W2 = (const float*)d_in[4];   // [256,256]
    const float* b2 = (const float*)d_in[5];   // [256]
    const int T = in_sizes[2] / 256 - 7;       // 288

    __bf16* W2S  = (__bf16*)d_ws;                         // 128 KB
    __bf16* Htab = (__bf16*)((char*)d_ws + 131072);       // 7*T*512 bytes
    int*    flag = (int*)((char*)d_ws + 131072 + (size_t)7 * T * 512);
    float*  out  = (float*)d_out;

    prep_all<<<7 * T + 64, 64, 0, stream>>>(W1, b1, W2, W2S, Htab, TE, flag, T);
    temb_gemm<<<M_TOTAL / BM, 256, 0, stream>>>(TE, Htab, W2S, b2, flag, out, T);
}